// Round 1
// baseline (497.859 us; speedup 1.0000x reference)
//
#include <hip/hip_runtime.h>
#include <hip/hip_fp16.h>

// LinearAttention (phi = elu+1). B=8 S=4096 D=512 H=8 DH=64.
// Round 5: GEMM restructure. The two MFMA GEMMs move from the 128^2-tile
// 2-barrier structure (measured 864 TF effective, MfmaUtil 38.7% = the m97
// ceiling) to a 256^2-tile, 8-wave, double-buffered pipeline with counted
// vmcnt (loads in flight across barriers, never drained to 0 in the loop).
// The bf16 hi/lo 3-pass split is reformulated as a single concat-K GEMM
// (K = 3*512 = 1536 over per-tile source pairs (Ah,Bh),(Ah,Bl),(Al,Bh)),
// halving LDS per K-tile so a 2-deep ring fits in 64 KB static LDS.
// All other kernels (prep_w, split_x, kv_stage1/2, attn_combine) verbatim
// from the fully verified round-4 kernel. Same swizzle / fragment / C-layout
// math as round 4 (measured SQ_LDS_BANK_CONFLICT = 0).
// ws: [x_hi 32|x_lo 32|Wt_hi 2|Wt_lo 2|Qf 32|Kf 32|V 32|KVp 17|Ksp|KV|Ksum]
// attn_hi/lo reuse x_hi/x_lo (dead after QKV gemm).

constexpr int Ss = 4096;
constexpr int Dd = 512;
constexpr int Hh = 8;
constexpr int Mtot = 8 * 4096;  // 32768
constexpr float EPSF = 1e-6f;

typedef short v8s __attribute__((ext_vector_type(8)));
typedef float v4f __attribute__((ext_vector_type(4)));

__device__ __forceinline__ short f2bf(float f) {  // RNE fp32 -> bf16
  unsigned u = __float_as_uint(f);
  u += 0x7fff + ((u >> 16) & 1);
  return (short)(u >> 16);
}
__device__ __forceinline__ float bf2f(short s) {
  return __uint_as_float(((unsigned)(unsigned short)s) << 16);
}
__device__ __forceinline__ void async_cp16(const void* g, void* l) {
  __builtin_amdgcn_global_load_lds((__attribute__((address_space(1))) void*)g,
                                   (__attribute__((address_space(3))) void*)l, 16, 0, 0);
}

// ---------- weight prep: W[512][512] -> Wt[n][k] bf16 hi/lo (4 matrices) ----------
__global__ __launch_bounds__(256) void prep_w(
    const float* __restrict__ W0, const float* __restrict__ W1,
    const float* __restrict__ W2, const float* __restrict__ W3,
    short* __restrict__ Th, short* __restrict__ Tl)
{
  const float* W = (blockIdx.z == 0) ? W0 : (blockIdx.z == 1) ? W1
                  : (blockIdx.z == 2) ? W2 : W3;
  short* th = Th + (size_t)blockIdx.z * 512 * 512;
  short* tl = Tl + (size_t)blockIdx.z * 512 * 512;
  __shared__ float tile[32][33];
  const int t = threadIdx.x;
  const int tx = t & 31, ty = t >> 5;  // 32 x 8
  const int k0 = blockIdx.x * 32, n0 = blockIdx.y * 32;
#pragma unroll
  for (int r = 0; r < 32; r += 8)
    tile[ty + r][tx] = W[(size_t)(k0 + ty + r) * 512 + n0 + tx];
  __syncthreads();
#pragma unroll
  for (int r = 0; r < 32; r += 8) {
    const float v = tile[tx][ty + r];  // = W[k0+tx][n0+ty+r]
    const short h = f2bf(v);
    const short l = f2bf(v - bf2f(h));
    th[(size_t)(n0 + ty + r) * 512 + k0 + tx] = h;
    tl[(size_t)(n0 + ty + r) * 512 + k0 + tx] = l;
  }
}

// ---------- x split: fp32 -> bf16 hi/lo ----------
__global__ __launch_bounds__(256) void split_x(
    const float* __restrict__ X, short* __restrict__ H, short* __restrict__ L, int n4)
{
  const int i = blockIdx.x * 256 + threadIdx.x;
  if (i >= n4) return;
  const float4 x = reinterpret_cast<const float4*>(X)[i];
  short4 h, l;
  h.x = f2bf(x.x); l.x = f2bf(x.x - bf2f(h.x));
  h.y = f2bf(x.y); l.y = f2bf(x.y - bf2f(h.y));
  h.z = f2bf(x.z); l.z = f2bf(x.z - bf2f(h.z));
  h.w = f2bf(x.w); l.w = f2bf(x.w - bf2f(h.w));
  reinterpret_cast<short4*>(H)[i] = h;
  reinterpret_cast<short4*>(L)[i] = l;
}

// ---------- staging: one 256x32-short tile of A and B into LDS ----------
// pA/pB already offset to the block's row0/col0. LDS dest is linear in
// (thread, c) order (global_load_lds requirement); the k-quad swizzle is
// applied on the GLOBAL source (pre-swizzled-source pattern, proven 0-conflict
// in round 4). 4 loads/thread/tile (A:2, B:2).
__device__ __forceinline__ void stage_tile(
    const short* __restrict__ pA, const short* __restrict__ pB,
    short* as, short* bs, int k0, int t)
{
#pragma unroll
  for (int c = 0; c < 2; ++c) {
    const int idx = t + c * 512;            // 0..1023
    const int row = idx >> 2;               // 0..255
    const int q = (idx & 3) ^ ((row >> 1) & 3);
    const size_t g = (size_t)row * 512 + k0 + q * 8;
    async_cp16(pA + g, as + idx * 8);
    async_cp16(pB + g, bs + idx * 8);
  }
}

// ---------- fused QKV GEMM, 256x256 tile, concat-K split, 2-deep pipeline ----
// grid (Mtot/256, 6): y = mat*2 + colhalf. phi for q,k; fp16 outputs.
// K-tiles kt in [0,48): pass = kt>>4 -> (Ah,Bh) / (Ah,Bl) / (Al,Bh); k0=(kt&15)*32.
__global__ __launch_bounds__(512, 2) void gemm_qkv(
    const short* __restrict__ Ah, const short* __restrict__ Al,
    const short* __restrict__ Wth, const short* __restrict__ Wtl,
    const float* __restrict__ bq, const float* __restrict__ bk,
    const float* __restrict__ bv,
    __half* __restrict__ Qf, __half* __restrict__ Kf, __half* __restrict__ Vv)
{
  __shared__ short As[2][256 * 32];  // 2 x 16 KB
  __shared__ short Bs[2][256 * 32];  // 2 x 16 KB   (total 64 KB)

  const int mat = blockIdx.y >> 1;
  const int col0 = (blockIdx.y & 1) * 256;
  const int row0 = blockIdx.x * 256;
  const float* bias = (mat == 0) ? bq : (mat == 1) ? bk : bv;
  __half* Co = (mat == 0) ? Qf : (mat == 1) ? Kf : Vv;
  const int act = (mat < 2);

  const short* Ahb = Ah + (size_t)row0 * 512;
  const short* Alb = Al + (size_t)row0 * 512;
  const short* Bhb = Wth + (size_t)mat * 512 * 512 + (size_t)col0 * 512;
  const short* Blb = Wtl + (size_t)mat * 512 * 512 + (size_t)col0 * 512;

  const int t = threadIdx.x;
  const int lane = t & 63;
  const int wv = t >> 6;                 // 8 waves
  const int wm = wv >> 2, wn = wv & 3;   // 2M x 4N -> per-wave 128x64 out
  const int mr = lane & 15, kq = lane >> 4;

  // loop-invariant fragment offsets (short-index), same swizzle as staging
  int a_off[8], b_off[4];
#pragma unroll
  for (int i = 0; i < 8; ++i) {
    const int ma = wm * 128 + i * 16 + mr;
    a_off[i] = ma * 32 + (kq ^ ((ma >> 1) & 3)) * 8;
  }
#pragma unroll
  for (int j = 0; j < 4; ++j) {
    const int nb = wn * 64 + j * 16 + mr;
    b_off[j] = nb * 32 + (kq ^ ((nb >> 1) & 3)) * 8;
  }

  v4f acc[8][4];
#pragma unroll
  for (int i = 0; i < 8; ++i)
#pragma unroll
    for (int j = 0; j < 4; ++j) acc[i][j] = (v4f){0.f, 0.f, 0.f, 0.f};

  // prologue: tile 0 in flight (4 loads/thread)
  stage_tile(Ahb, Bhb, As[0], Bs[0], 0, t);

  for (int kt = 0; kt < 48; ++kt) {
    const int cur = kt & 1;
    // stage next tile early (into the buffer everyone finished last iter),
    // then counted wait: tile kt landed, tile kt+1 stays in flight.
    if (kt + 1 < 48) {
      const int nx = kt + 1;
      const int pass = nx >> 4;
      const short* pA = (pass == 2) ? Alb : Ahb;
      const short* pB = (pass == 1) ? Blb : Bhb;
      stage_tile(pA, pB, As[cur ^ 1], Bs[cur ^ 1], (nx & 15) * 32, t);
      asm volatile("s_waitcnt vmcnt(4)" ::: "memory");
    } else {
      asm volatile("s_waitcnt vmcnt(0)" ::: "memory");
    }
    __builtin_amdgcn_s_barrier();          // everyone's tile-kt loads landed
    asm volatile("" ::: "memory");

    v8s fb[4];
#pragma unroll
    for (int j = 0; j < 4; ++j)
      fb[j] = *reinterpret_cast<const v8s*>(&Bs[cur][b_off[j]]);
    __builtin_amdgcn_s_setprio(1);
#pragma unroll
    for (int i = 0; i < 8; ++i) {
      const v8s fa = *reinterpret_cast<const v8s*>(&As[cur][a_off[i]]);
#pragma unroll
      for (int j = 0; j < 4; ++j)
        acc[i][j] = __builtin_amdgcn_mfma_f32_16x16x32_bf16(fa, fb[j], acc[i][j], 0, 0, 0);
    }
    __builtin_amdgcn_s_setprio(0);
    asm volatile("" ::: "memory");
    __builtin_amdgcn_s_barrier();          // all waves done reading buf[cur]
  }

  // epilogue: C/D layout col = lane&15, row = kq*4 + r (round-4 verbatim math)
#pragma unroll
  for (int j = 0; j < 4; ++j) {
    const int nc = col0 + wn * 64 + j * 16 + mr;
    const float bz = bias[nc];
#pragma unroll
    for (int i = 0; i < 8; ++i) {
      const int mbase = row0 + wm * 128 + i * 16 + kq * 4;
#pragma unroll
      for (int r = 0; r < 4; ++r) {
        float v = acc[i][j][r] + bz;
        if (act) v = (v > 0.f) ? (v + 1.f) : __expf(v);
        Co[(size_t)(mbase + r) * 512 + nc] = __float2half(v);
      }
    }
  }
}

// ---------- final GEMM: out = attn @ Wo + bo, same 256^2 pipelined structure ----
__global__ __launch_bounds__(512, 2) void gemm_split(
    const short* __restrict__ Ah, const short* __restrict__ Al,
    const short* __restrict__ Bh, const short* __restrict__ Bl,
    const float* __restrict__ bias, float* __restrict__ Cf)
{
  __shared__ short As[2][256 * 32];
  __shared__ short Bs[2][256 * 32];

  const int col0 = blockIdx.y * 256;
  const int row0 = blockIdx.x * 256;

  const short* Ahb = Ah + (size_t)row0 * 512;
  const short* Alb = Al + (size_t)row0 * 512;
  const short* Bhb = Bh + (size_t)col0 * 512;
  const short* Blb = Bl + (size_t)col0 * 512;

  const int t = threadIdx.x;
  const int lane = t & 63;
  const int wv = t >> 6;
  const int wm = wv >> 2, wn = wv & 3;
  const int mr = lane & 15, kq = lane >> 4;

  int a_off[8], b_off[4];
#pragma unroll
  for (int i = 0; i < 8; ++i) {
    const int ma = wm * 128 + i * 16 + mr;
    a_off[i] = ma * 32 + (kq ^ ((ma >> 1) & 3)) * 8;
  }
#pragma unroll
  for (int j = 0; j < 4; ++j) {
    const int nb = wn * 64 + j * 16 + mr;
    b_off[j] = nb * 32 + (kq ^ ((nb >> 1) & 3)) * 8;
  }

  v4f acc[8][4];
#pragma unroll
  for (int i = 0; i < 8; ++i)
#pragma unroll
    for (int j = 0; j < 4; ++j) acc[i][j] = (v4f){0.f, 0.f, 0.f, 0.f};

  stage_tile(Ahb, Bhb, As[0], Bs[0], 0, t);

  for (int kt = 0; kt < 48; ++kt) {
    const int cur = kt & 1;
    if (kt + 1 < 48) {
      const int nx = kt + 1;
      const int pass = nx >> 4;
      const short* pA = (pass == 2) ? Alb : Ahb;
      const short* pB = (pass == 1) ? Blb : Bhb;
      stage_tile(pA, pB, As[cur ^ 1], Bs[cur ^ 1], (nx & 15) * 32, t);
      asm volatile("s_waitcnt vmcnt(4)" ::: "memory");
    } else {
      asm volatile("s_waitcnt vmcnt(0)" ::: "memory");
    }
    __builtin_amdgcn_s_barrier();
    asm volatile("" ::: "memory");

    v8s fb[4];
#pragma unroll
    for (int j = 0; j < 4; ++j)
      fb[j] = *reinterpret_cast<const v8s*>(&Bs[cur][b_off[j]]);
    __builtin_amdgcn_s_setprio(1);
#pragma unroll
    for (int i = 0; i < 8; ++i) {
      const v8s fa = *reinterpret_cast<const v8s*>(&As[cur][a_off[i]]);
#pragma unroll
      for (int j = 0; j < 4; ++j)
        acc[i][j] = __builtin_amdgcn_mfma_f32_16x16x32_bf16(fa, fb[j], acc[i][j], 0, 0, 0);
    }
    __builtin_amdgcn_s_setprio(0);
    asm volatile("" ::: "memory");
    __builtin_amdgcn_s_barrier();
  }

#pragma unroll
  for (int j = 0; j < 4; ++j) {
    const int nc = col0 + wn * 64 + j * 16 + mr;
    const float bz = bias[nc];
#pragma unroll
    for (int i = 0; i < 8; ++i) {
      const int mbase = row0 + wm * 128 + i * 16 + kq * 4;
#pragma unroll
      for (int r = 0; r < 4; ++r) Cf[(size_t)(mbase + r) * 512 + nc] = acc[i][j][r] + bz;
    }
  }
}

// ---------- KV stage 1 (round-4 verbatim): partial Kf^T@V and sum Kf ----------
__global__ __launch_bounds__(256) void kv_stage1(
    const __half* __restrict__ Kf, const __half* __restrict__ V,
    float* __restrict__ KVp, float* __restrict__ Ksp)
{
  const int sc = blockIdx.x, bh = blockIdx.y;
  const int b = bh >> 3, h = bh & 7;
  __shared__ float Ks[64][68];
  __shared__ float Vs[64][68];
  const int tid = threadIdx.x;
  const int dx = (tid >> 4) * 4;
  const int mx = (tid & 15) * 4;
  float acc[4][4];
#pragma unroll
  for (int i = 0; i < 4; ++i)
#pragma unroll
    for (int j = 0; j < 4; ++j) acc[i][j] = 0.f;
  float ksum_acc = 0.f;
  const size_t base = (size_t)b * Ss * Dd + (size_t)h * 64;

  for (int s0 = sc * 256; s0 < sc * 256 + 256; s0 += 64) {
#pragma unroll
    for (int l = 0; l < 2; ++l) {
      const int idx = tid + l * 256;
      const int rr = idx >> 3, cq = idx & 7;
      const size_t g = base + (size_t)(s0 + rr) * Dd + cq * 8;
      const __half2* k2 = reinterpret_cast<const __half2*>(Kf + g);
      const __half2* v2 = reinterpret_cast<const __half2*>(V + g);
#pragma unroll
      for (int u = 0; u < 4; ++u) {
        const float2 kf = __half22float2(k2[u]);
        const float2 vf = __half22float2(v2[u]);
        Ks[rr][cq * 8 + u * 2] = kf.x; Ks[rr][cq * 8 + u * 2 + 1] = kf.y;
        Vs[rr][cq * 8 + u * 2] = vf.x; Vs[rr][cq * 8 + u * 2 + 1] = vf.y;
      }
    }
    __syncthreads();
#pragma unroll 4
    for (int s = 0; s < 64; ++s) {
      const float4 kd = *reinterpret_cast<const float4*>(&Ks[s][dx]);
      const float4 vm = *reinterpret_cast<const float4*>(&Vs[s][mx]);
      const float ka[4] = {kd.x, kd.y, kd.z, kd.w};
      const float va[4] = {vm.x, vm.y, vm.z, vm.w};
#pragma unroll
      for (int i = 0; i < 4; ++i)
#pragma unroll
        for (int j = 0; j < 4; ++j) acc[i][j] = fmaf(ka[i], va[j], acc[i][j]);
    }
    if (tid < 64) {
#pragma unroll 8
      for (int s = 0; s < 64; ++s) ksum_acc += Ks[s][tid];
    }
    __syncthreads();
  }

  const size_t pb = (size_t)(sc * 64 + bh);
#pragma unroll
  for (int i = 0; i < 4; ++i) {
    const float4 ov = {acc[i][0], acc[i][1], acc[i][2], acc[i][3]};
    *reinterpret_cast<float4*>(&KVp[(pb * 64 + dx + i) * 64 + mx]) = ov;
  }
  if (tid < 64) Ksp[pb * 64 + tid] = ksum_acc;
}

// ---------- KV stage 2 (round-4 verbatim): sum 16 partials ----------
__global__ __launch_bounds__(256) void kv_stage2(
    const float* __restrict__ KVp, const float* __restrict__ Ksp,
    float* __restrict__ KV, float* __restrict__ Ksum)
{
  const int bh = blockIdx.x, t = threadIdx.x;
  for (int e = t; e < 4096; e += 256) {
    float s = 0.f;
#pragma unroll
    for (int sc = 0; sc < 16; ++sc) s += KVp[((size_t)(sc * 64 + bh) << 12) + e];
    KV[(size_t)bh * 4096 + e] = s;
  }
  if (t < 64) {
    float s = 0.f;
#pragma unroll
    for (int sc = 0; sc < 16; ++sc) s += Ksp[(size_t)(sc * 64 + bh) * 64 + t];
    Ksum[bh * 64 + t] = s;
  }
}

// ---------- attn (round-4 verbatim): Z * (Qf @ KV), bf16 hi/lo split out -----
__global__ __launch_bounds__(256) void attn_combine(
    const __half* __restrict__ Qf, const float* __restrict__ KV,
    const float* __restrict__ Ksum, short* __restrict__ Oh, short* __restrict__ Ol)
{
  const int h = blockIdx.y;
  const int r0 = blockIdx.x * 64;
  const int b = r0 >> 12;
  const int bh = b * Hh + h;
  __shared__ float Qs[64][68];
  __shared__ float KVs[64][68];
  __shared__ float Ksums[64];
  __shared__ float Zs[64];
  const int tid = threadIdx.x;

#pragma unroll
  for (int l = 0; l < 2; ++l) {
    const int idx = tid + l * 256;
    const int rr = idx >> 3, cq = idx & 7;
    const __half2* q2 = reinterpret_cast<const __half2*>(
        Qf + (size_t)(r0 + rr) * Dd + h * 64 + cq * 8);
#pragma unroll
    for (int u = 0; u < 4; ++u) {
      const float2 qf = __half22float2(q2[u]);
      Qs[rr][cq * 8 + u * 2] = qf.x; Qs[rr][cq * 8 + u * 2 + 1] = qf.y;
    }
  }
#pragma unroll
  for (int l = 0; l < 4; ++l) {
    const int idx = tid + l * 256;
    const int rr = idx >> 4, cq = idx & 15;
    *reinterpret_cast<float4*>(&KVs[rr][cq * 4]) = *reinterpret_cast<const float4*>(
        &KV[(size_t)bh * 4096 + rr * 64 + cq * 4]);
  }
  if (tid < 64) Ksums[tid] = Ksum[bh * 64 + tid];
  __syncthreads();

  if (tid < 64) {
    float z = 0.f;
#pragma unroll 8
    for (int d = 0; d < 64; ++d) z = fmaf(Qs[tid][d], Ksums[d], z);
    Zs[tid] = 1.f / (z + EPSF);
  }
  __syncthreads();

  const int rx = (tid >> 4) * 4, mx = (tid & 15) * 4;
  float acc[4][4];
#pragma unroll
  for (int i = 0; i < 4; ++i)
#pragma unroll
    for (int j = 0; j < 4; ++j) acc[i][j] = 0.f;

#pragma unroll 4
  for (int d = 0; d < 64; ++d) {
    const float4 vm = *reinterpret_cast<const float4*>(&KVs[d][mx]);
    const float va[4] = {vm.x, vm.y, vm.z, vm.w};
#pragma unroll
    for (int i = 0; i < 4; ++i) {
      const float q = Qs[rx + i][d];
#pragma unroll
      for (int j = 0; j < 4; ++j) acc[i][j] = fmaf(q, va[j], acc[i][j]);
    }
  }

#pragma unroll
  for (int i = 0; i < 4; ++i) {
    const float z = Zs[rx + i];
    short4 hv, lv;
    float o;
    o = acc[i][0] * z; hv.x = f2bf(o); lv.x = f2bf(o - bf2f(hv.x));
    o = acc[i][1] * z; hv.y = f2bf(o); lv.y = f2bf(o - bf2f(hv.y));
    o = acc[i][2] * z; hv.z = f2bf(o); lv.z = f2bf(o - bf2f(hv.z));
    o = acc[i][3] * z; hv.w = f2bf(o); lv.w = f2bf(o - bf2f(hv.w));
    const size_t off = (size_t)(r0 + rx + i) * Dd + h * 64 + mx;
    *reinterpret_cast<short4*>(&Oh[off]) = hv;
    *reinterpret_cast<short4*>(&Ol[off]) = lv;
  }
}

extern "C" void kernel_launch(void* const* d_in, const int* in_sizes, int n_in,
                              void* d_out, int out_size, void* d_ws, size_t ws_size,
                              hipStream_t stream) {
  const float* x  = (const float*)d_in[0];
  const float* Wq = (const float*)d_in[1];
  const float* bq = (const float*)d_in[2];
  const float* Wk = (const float*)d_in[3];
  const float* bk = (const float*)d_in[4];
  const float* Wv = (const float*)d_in[5];
  const float* bv = (const float*)d_in[6];
  const float* Wo = (const float*)d_in[7];
  const float* bo = (const float*)d_in[8];
  float* out = (float*)d_out;

  char* ws = (char*)d_ws;
  const size_t MB = (size_t)1 << 20;
  short*  x_hi  = (short*)(ws);              // 32 MB (later: attn_hi)
  short*  x_lo  = (short*)(ws + 32 * MB);    // 32 MB (later: attn_lo)
  short*  Wt_hi = (short*)(ws + 64 * MB);    // 2 MB (4 x 512x512)
  short*  Wt_lo = (short*)(ws + 66 * MB);    // 2 MB
  __half* Qf    = (__half*)(ws + 68 * MB);   // 32 MB
  __half* Kf    = (__half*)(ws + 100 * MB);  // 32 MB
  __half* Vv    = (__half*)(ws + 132 * MB);  // 32 MB
  float*  KVp   = (float*)(ws + 164 * MB);   // 17 MB
  float*  Ksp   = (float*)(ws + 181 * MB);   // 256 KB
  float*  KV    = (float*)(ws + 182 * MB);   // 1 MB
  float*  Ksum  = (float*)(ws + 183 * MB);   // 16 KB
  short*  attn_hi = x_hi;
  short*  attn_lo = x_lo;
  const size_t WSTEP = (size_t)512 * 512;

  prep_w<<<dim3(16, 16, 4), 256, 0, stream>>>(Wq, Wk, Wv, Wo, Wt_hi, Wt_lo);
  split_x<<<Mtot * Dd / 4 / 256, 256, 0, stream>>>(x, x_hi, x_lo, Mtot * Dd / 4);

  gemm_qkv<<<dim3(Mtot / 256, 6), 512, 0, stream>>>(
      x_hi, x_lo, Wt_hi, Wt_lo, bq, bk, bv, Qf, Kf, Vv);

  kv_stage1<<<dim3(16, 64), 256, 0, stream>>>(Kf, Vv, KVp, Ksp);
  kv_stage2<<<64, 256, 0, stream>>>(KVp, Ksp, KV, Ksum);
  attn_combine<<<dim3(Mtot / 64, Hh), 256, 0, stream>>>(Qf, KV, Ksum, attn_hi, attn_lo);

  gemm_split<<<dim3(Mtot / 256, 2), 512, 0, stream>>>(
      attn_hi, attn_lo, Wt_hi + 3 * WSTEP, Wt_lo + 3 * WSTEP, bo, out);
}

// Round 2
// 466.549 us; speedup vs baseline: 1.0671x; 1.0671x over previous
//
#include <hip/hip_runtime.h>
#include <hip/hip_fp16.h>

// LinearAttention (phi = elu+1). B=8 S=4096 D=512 H=8 DH=64.
// Round 6: full 8-phase port (T3+T4+T5) for both MFMA GEMMs.
// Round-5 diagnosis: 2-phase @256^2 = 644 TF = the known 2-phase plateau
// (m230/m248). This round implements the m201-style schedule: BK=64 K-tiles
// (two BK=32 sub-tiles, keeping the verified 0-conflict q-XOR swizzle),
// 2-deep LDS ring (128 KB, 1 block/CU), 4 phases per K-tile each
// {ds_read subtile | stage 1 chunk | barrier | setprio+16 MFMA | barrier},
// vmcnt counted once per K-tile (2 loads stay in flight, never drain to 0
// mid-loop). Grid: 768 blocks = exactly 3 dispatch waves; gemm_split 256 = 1.
// Concat-K hi/lo split unchanged: K=1536 over (Ah,Bh),(Ah,Bl),(Al,Bh).
// All non-GEMM kernels verbatim from the verified round-4/5 versions.
// ws: [x_hi 32|x_lo 32|Wt_hi 2|Wt_lo 2|Qf 32|Kf 32|V 32|KVp 17|Ksp|KV|Ksum]

constexpr int Ss = 4096;
constexpr int Dd = 512;
constexpr int Hh = 8;
constexpr int Mtot = 8 * 4096;  // 32768
constexpr float EPSF = 1e-6f;

typedef short v8s __attribute__((ext_vector_type(8)));
typedef float v4f __attribute__((ext_vector_type(4)));

__device__ __forceinline__ short f2bf(float f) {  // RNE fp32 -> bf16
  unsigned u = __float_as_uint(f);
  u += 0x7fff + ((u >> 16) & 1);
  return (short)(u >> 16);
}
__device__ __forceinline__ float bf2f(short s) {
  return __uint_as_float(((unsigned)(unsigned short)s) << 16);
}
__device__ __forceinline__ void async_cp16(const void* g, void* l) {
  __builtin_amdgcn_global_load_lds((__attribute__((address_space(1))) void*)g,
                                   (__attribute__((address_space(3))) void*)l, 16, 0, 0);
}

// ---------- weight prep: W[512][512] -> Wt[n][k] bf16 hi/lo (4 matrices) ----------
__global__ __launch_bounds__(256) void prep_w(
    const float* __restrict__ W0, const float* __restrict__ W1,
    const float* __restrict__ W2, const float* __restrict__ W3,
    short* __restrict__ Th, short* __restrict__ Tl)
{
  const float* W = (blockIdx.z == 0) ? W0 : (blockIdx.z == 1) ? W1
                  : (blockIdx.z == 2) ? W2 : W3;
  short* th = Th + (size_t)blockIdx.z * 512 * 512;
  short* tl = Tl + (size_t)blockIdx.z * 512 * 512;
  __shared__ float tile[32][33];
  const int t = threadIdx.x;
  const int tx = t & 31, ty = t >> 5;  // 32 x 8
  const int k0 = blockIdx.x * 32, n0 = blockIdx.y * 32;
#pragma unroll
  for (int r = 0; r < 32; r += 8)
    tile[ty + r][tx] = W[(size_t)(k0 + ty + r) * 512 + n0 + tx];
  __syncthreads();
#pragma unroll
  for (int r = 0; r < 32; r += 8) {
    const float v = tile[tx][ty + r];  // = W[k0+tx][n0+ty+r]
    const short h = f2bf(v);
    const short l = f2bf(v - bf2f(h));
    th[(size_t)(n0 + ty + r) * 512 + k0 + tx] = h;
    tl[(size_t)(n0 + ty + r) * 512 + k0 + tx] = l;
  }
}

// ---------- x split: fp32 -> bf16 hi/lo ----------
__global__ __launch_bounds__(256) void split_x(
    const float* __restrict__ X, short* __restrict__ H, short* __restrict__ L, int n4)
{
  const int i = blockIdx.x * 256 + threadIdx.x;
  if (i >= n4) return;
  const float4 x = reinterpret_cast<const float4*>(X)[i];
  short4 h, l;
  h.x = f2bf(x.x); l.x = f2bf(x.x - bf2f(h.x));
  h.y = f2bf(x.y); l.y = f2bf(x.y - bf2f(h.y));
  h.z = f2bf(x.z); l.z = f2bf(x.z - bf2f(h.z));
  h.w = f2bf(x.w); l.w = f2bf(x.w - bf2f(h.w));
  reinterpret_cast<short4*>(H)[i] = h;
  reinterpret_cast<short4*>(L)[i] = l;
}

// ---------- staging chunk: 512 threads write 8 KB of A + 8 KB of B ----------
// Chunk = (sub s, row-half rh): rows rh*128..+127 of one BK=32 sub-tile.
// LDS dest per lane = base + lane*16B (global_load_lds linear requirement):
// d = rh*4096 + t*8 shorts == (row*4 + q)*8 with row = rh*128 + t>>2, q = t&3.
// k-quad swizzle (q ^ (row>>1)&3) applied on the GLOBAL source (verified
// 0-conflict pattern). kb = tile_k_base + s*32.
__device__ __forceinline__ void stage_chunk(
    const short* __restrict__ pA, const short* __restrict__ pB,
    short* asub, short* bsub, int kb, int rh, int t)
{
  const int row = rh * 128 + (t >> 2);
  const int q = t & 3;
  const int qs = q ^ ((row >> 1) & 3);
  const size_t g = (size_t)row * 512 + kb + qs * 8;
  const int d = rh * 4096 + t * 8;
  async_cp16(pA + g, asub + d);
  async_cp16(pB + g, bsub + d);
}

// ---------- 8-phase K-loop: 24 K-tiles (BK=64), 4 phases each ----------
// Per wave (128x64 output): phase p computes m-frags {2p, 2p+1} x all 4 n x
// both k-subs = 16 MFMA. Phase 0 additionally reads all 8 B-frags (held in
// registers for the tile). One counted vmcnt per tile at phase 0.
__device__ __forceinline__ void kloop_8ph(
    const short* __restrict__ Ahb, const short* __restrict__ Alb,
    const short* __restrict__ Bhb, const short* __restrict__ Blb,
    short* asb, short* bsb,  // LDS bases, layout [2 buf][2 sub][8192]
    int wm, int wn, int mr, int kq, int t,
    v4f (&acc)[8][4])
{
  constexpr int NT = 24;
#pragma unroll
  for (int i = 0; i < 8; ++i)
#pragma unroll
    for (int j = 0; j < 4; ++j) acc[i][j] = (v4f){0.f, 0.f, 0.f, 0.f};

  int a_off[8], b_off[4];
#pragma unroll
  for (int i = 0; i < 8; ++i) {
    const int ma = wm * 128 + i * 16 + mr;
    a_off[i] = ma * 32 + (kq ^ ((ma >> 1) & 3)) * 8;
  }
#pragma unroll
  for (int j = 0; j < 4; ++j) {
    const int nb = wn * 64 + j * 16 + mr;
    b_off[j] = nb * 32 + (kq ^ ((nb >> 1) & 3)) * 8;
  }

  // prologue: stage tile 0 fully (8 loads/thread)
#pragma unroll
  for (int c = 0; c < 4; ++c)
    stage_chunk(Ahb, Bhb, asb + (c & 1) * 8192, bsb + (c & 1) * 8192,
                (c & 1) * 32, c >> 1, t);

  for (int kt = 0; kt < NT; ++kt) {
    const int cur = kt & 1;
    const short* as0 = asb + cur * 16384;
    const short* as1 = as0 + 8192;
    const short* bs0 = bsb + cur * 16384;
    const short* bs1 = bs0 + 8192;
    short* An = asb + (cur ^ 1) * 16384;
    short* Bn = bsb + (cur ^ 1) * 16384;
    const int nx = kt + 1;
    const int pass = nx >> 3;  // 8 tiles per 512-K pass
    const short* pA = (pass == 2) ? Alb : Ahb;
    const short* pB = (pass == 1) ? Blb : Bhb;
    const int kb = (nx & 7) * 64;

    // ---- phase 0 ----
    if (nx < NT) {
      stage_chunk(pA, pB, An, Bn, kb, 0, t);  // chunk 0: s=0, rh=0
      // all of tile kt landed; the 2 chunk-0 loads stay in flight
      asm volatile("s_waitcnt vmcnt(2)" ::: "memory");
    } else {
      asm volatile("s_waitcnt vmcnt(0)" ::: "memory");
    }
    __builtin_amdgcn_s_barrier();
    asm volatile("" ::: "memory");

    v8s fb[4][2];
#pragma unroll
    for (int j = 0; j < 4; ++j) {
      fb[j][0] = *reinterpret_cast<const v8s*>(&bs0[b_off[j]]);
      fb[j][1] = *reinterpret_cast<const v8s*>(&bs1[b_off[j]]);
    }
    {
      const v8s fa00 = *reinterpret_cast<const v8s*>(&as0[a_off[0]]);
      const v8s fa01 = *reinterpret_cast<const v8s*>(&as1[a_off[0]]);
      const v8s fa10 = *reinterpret_cast<const v8s*>(&as0[a_off[1]]);
      const v8s fa11 = *reinterpret_cast<const v8s*>(&as1[a_off[1]]);
      __builtin_amdgcn_s_setprio(1);
#pragma unroll
      for (int j = 0; j < 4; ++j) {
        acc[0][j] = __builtin_amdgcn_mfma_f32_16x16x32_bf16(fa00, fb[j][0], acc[0][j], 0, 0, 0);
        acc[0][j] = __builtin_amdgcn_mfma_f32_16x16x32_bf16(fa01, fb[j][1], acc[0][j], 0, 0, 0);
        acc[1][j] = __builtin_amdgcn_mfma_f32_16x16x32_bf16(fa10, fb[j][0], acc[1][j], 0, 0, 0);
        acc[1][j] = __builtin_amdgcn_mfma_f32_16x16x32_bf16(fa11, fb[j][1], acc[1][j], 0, 0, 0);
      }
      __builtin_amdgcn_s_setprio(0);
    }
    asm volatile("" ::: "memory");
    __builtin_amdgcn_s_barrier();

    // ---- phases 1..3 ----
#pragma unroll
    for (int p = 1; p < 4; ++p) {
      const v8s fa00 = *reinterpret_cast<const v8s*>(&as0[a_off[2 * p]]);
      const v8s fa01 = *reinterpret_cast<const v8s*>(&as1[a_off[2 * p]]);
      const v8s fa10 = *reinterpret_cast<const v8s*>(&as0[a_off[2 * p + 1]]);
      const v8s fa11 = *reinterpret_cast<const v8s*>(&as1[a_off[2 * p + 1]]);
      if (nx < NT)
        stage_chunk(pA, pB, An + (p & 1) * 8192, Bn + (p & 1) * 8192,
                    kb + (p & 1) * 32, p >> 1, t);
      __builtin_amdgcn_s_barrier();
      asm volatile("" ::: "memory");
      __builtin_amdgcn_s_setprio(1);
#pragma unroll
      for (int j = 0; j < 4; ++j) {
        acc[2 * p][j] =
            __builtin_amdgcn_mfma_f32_16x16x32_bf16(fa00, fb[j][0], acc[2 * p][j], 0, 0, 0);
        acc[2 * p][j] =
            __builtin_amdgcn_mfma_f32_16x16x32_bf16(fa01, fb[j][1], acc[2 * p][j], 0, 0, 0);
        acc[2 * p + 1][j] =
            __builtin_amdgcn_mfma_f32_16x16x32_bf16(fa10, fb[j][0], acc[2 * p + 1][j], 0, 0, 0);
        acc[2 * p + 1][j] =
            __builtin_amdgcn_mfma_f32_16x16x32_bf16(fa11, fb[j][1], acc[2 * p + 1][j], 0, 0, 0);
      }
      __builtin_amdgcn_s_setprio(0);
      asm volatile("" ::: "memory");
      __builtin_amdgcn_s_barrier();
    }
  }
}

// ---------- fused QKV GEMM, 256x256 tile, 8-phase pipeline ----
// grid (Mtot/256, 6): y = mat*2 + colhalf. phi for q,k; fp16 outputs.
__global__ __launch_bounds__(512, 2) void gemm_qkv(
    const short* __restrict__ Ah, const short* __restrict__ Al,
    const short* __restrict__ Wth, const short* __restrict__ Wtl,
    const float* __restrict__ bq, const float* __restrict__ bk,
    const float* __restrict__ bv,
    __half* __restrict__ Qf, __half* __restrict__ Kf, __half* __restrict__ Vv)
{
  __shared__ __align__(16) short As[2][2][8192];  // 64 KB
  __shared__ __align__(16) short Bs[2][2][8192];  // 64 KB

  const int mat = blockIdx.y >> 1;
  const int col0 = (blockIdx.y & 1) * 256;
  const int row0 = blockIdx.x * 256;
  const float* bias = (mat == 0) ? bq : (mat == 1) ? bk : bv;
  __half* Co = (mat == 0) ? Qf : (mat == 1) ? Kf : Vv;
  const int act = (mat < 2);

  const short* Ahb = Ah + (size_t)row0 * 512;
  const short* Alb = Al + (size_t)row0 * 512;
  const short* Bhb = Wth + (size_t)mat * 512 * 512 + (size_t)col0 * 512;
  const short* Blb = Wtl + (size_t)mat * 512 * 512 + (size_t)col0 * 512;

  const int t = threadIdx.x;
  const int lane = t & 63;
  const int wv = t >> 6;                 // 8 waves
  const int wm = wv >> 2, wn = wv & 3;   // 2M x 4N -> per-wave 128x64 out
  const int mr = lane & 15, kq = lane >> 4;

  v4f acc[8][4];
  kloop_8ph(Ahb, Alb, Bhb, Blb, &As[0][0][0], &Bs[0][0][0], wm, wn, mr, kq, t, acc);

  // epilogue: C/D layout col = lane&15, row = kq*4 + r (verified math)
#pragma unroll
  for (int j = 0; j < 4; ++j) {
    const int nc = col0 + wn * 64 + j * 16 + mr;
    const float bz = bias[nc];
#pragma unroll
    for (int i = 0; i < 8; ++i) {
      const int mbase = row0 + wm * 128 + i * 16 + kq * 4;
#pragma unroll
      for (int r = 0; r < 4; ++r) {
        float v = acc[i][j][r] + bz;
        if (act) v = (v > 0.f) ? (v + 1.f) : __expf(v);
        Co[(size_t)(mbase + r) * 512 + nc] = __float2half(v);
      }
    }
  }
}

// ---------- final GEMM: out = attn @ Wo + bo, same 8-phase structure ----
__global__ __launch_bounds__(512, 2) void gemm_split(
    const short* __restrict__ Ah, const short* __restrict__ Al,
    const short* __restrict__ Bh, const short* __restrict__ Bl,
    const float* __restrict__ bias, float* __restrict__ Cf)
{
  __shared__ __align__(16) short As[2][2][8192];
  __shared__ __align__(16) short Bs[2][2][8192];

  const int col0 = blockIdx.y * 256;
  const int row0 = blockIdx.x * 256;

  const short* Ahb = Ah + (size_t)row0 * 512;
  const short* Alb = Al + (size_t)row0 * 512;
  const short* Bhb = Bh + (size_t)col0 * 512;
  const short* Blb = Bl + (size_t)col0 * 512;

  const int t = threadIdx.x;
  const int lane = t & 63;
  const int wv = t >> 6;
  const int wm = wv >> 2, wn = wv & 3;
  const int mr = lane & 15, kq = lane >> 4;

  v4f acc[8][4];
  kloop_8ph(Ahb, Alb, Bhb, Blb, &As[0][0][0], &Bs[0][0][0], wm, wn, mr, kq, t, acc);

#pragma unroll
  for (int j = 0; j < 4; ++j) {
    const int nc = col0 + wn * 64 + j * 16 + mr;
    const float bz = bias[nc];
#pragma unroll
    for (int i = 0; i < 8; ++i) {
      const int mbase = row0 + wm * 128 + i * 16 + kq * 4;
#pragma unroll
      for (int r = 0; r < 4; ++r) Cf[(size_t)(mbase + r) * 512 + nc] = acc[i][j][r] + bz;
    }
  }
}

// ---------- KV stage 1 (verbatim): partial Kf^T@V and sum Kf ----------
__global__ __launch_bounds__(256) void kv_stage1(
    const __half* __restrict__ Kf, const __half* __restrict__ V,
    float* __restrict__ KVp, float* __restrict__ Ksp)
{
  const int sc = blockIdx.x, bh = blockIdx.y;
  const int b = bh >> 3, h = bh & 7;
  __shared__ float Ks[64][68];
  __shared__ float Vs[64][68];
  const int tid = threadIdx.x;
  const int dx = (tid >> 4) * 4;
  const int mx = (tid & 15) * 4;
  float acc[4][4];
#pragma unroll
  for (int i = 0; i < 4; ++i)
#pragma unroll
    for (int j = 0; j < 4; ++j) acc[i][j] = 0.f;
  float ksum_acc = 0.f;
  const size_t base = (size_t)b * Ss * Dd + (size_t)h * 64;

  for (int s0 = sc * 256; s0 < sc * 256 + 256; s0 += 64) {
#pragma unroll
    for (int l = 0; l < 2; ++l) {
      const int idx = tid + l * 256;
      const int rr = idx >> 3, cq = idx & 7;
      const size_t g = base + (size_t)(s0 + rr) * Dd + cq * 8;
      const __half2* k2 = reinterpret_cast<const __half2*>(Kf + g);
      const __half2* v2 = reinterpret_cast<const __half2*>(V + g);
#pragma unroll
      for (int u = 0; u < 4; ++u) {
        const float2 kf = __half22float2(k2[u]);
        const float2 vf = __half22float2(v2[u]);
        Ks[rr][cq * 8 + u * 2] = kf.x; Ks[rr][cq * 8 + u * 2 + 1] = kf.y;
        Vs[rr][cq * 8 + u * 2] = vf.x; Vs[rr][cq * 8 + u * 2 + 1] = vf.y;
      }
    }
    __syncthreads();
#pragma unroll 4
    for (int s = 0; s < 64; ++s) {
      const float4 kd = *reinterpret_cast<const float4*>(&Ks[s][dx]);
      const float4 vm = *reinterpret_cast<const float4*>(&Vs[s][mx]);
      const float ka[4] = {kd.x, kd.y, kd.z, kd.w};
      const float va[4] = {vm.x, vm.y, vm.z, vm.w};
#pragma unroll
      for (int i = 0; i < 4; ++i)
#pragma unroll
        for (int j = 0; j < 4; ++j) acc[i][j] = fmaf(ka[i], va[j], acc[i][j]);
    }
    if (tid < 64) {
#pragma unroll 8
      for (int s = 0; s < 64; ++s) ksum_acc += Ks[s][tid];
    }
    __syncthreads();
  }

  const size_t pb = (size_t)(sc * 64 + bh);
#pragma unroll
  for (int i = 0; i < 4; ++i) {
    const float4 ov = {acc[i][0], acc[i][1], acc[i][2], acc[i][3]};
    *reinterpret_cast<float4*>(&KVp[(pb * 64 + dx + i) * 64 + mx]) = ov;
  }
  if (tid < 64) Ksp[pb * 64 + tid] = ksum_acc;
}

// ---------- KV stage 2 (verbatim): sum 16 partials ----------
__global__ __launch_bounds__(256) void kv_stage2(
    const float* __restrict__ KVp, const float* __restrict__ Ksp,
    float* __restrict__ KV, float* __restrict__ Ksum)
{
  const int bh = blockIdx.x, t = threadIdx.x;
  for (int e = t; e < 4096; e += 256) {
    float s = 0.f;
#pragma unroll
    for (int sc = 0; sc < 16; ++sc) s += KVp[((size_t)(sc * 64 + bh) << 12) + e];
    KV[(size_t)bh * 4096 + e] = s;
  }
  if (t < 64) {
    float s = 0.f;
#pragma unroll
    for (int sc = 0; sc < 16; ++sc) s += Ksp[(size_t)(sc * 64 + bh) * 64 + t];
    Ksum[bh * 64 + t] = s;
  }
}

// ---------- attn (verbatim): Z * (Qf @ KV), bf16 hi/lo split out -----
__global__ __launch_bounds__(256) void attn_combine(
    const __half* __restrict__ Qf, const float* __restrict__ KV,
    const float* __restrict__ Ksum, short* __restrict__ Oh, short* __restrict__ Ol)
{
  const int h = blockIdx.y;
  const int r0 = blockIdx.x * 64;
  const int b = r0 >> 12;
  const int bh = b * Hh + h;
  __shared__ float Qs[64][68];
  __shared__ float KVs[64][68];
  __shared__ float Ksums[64];
  __shared__ float Zs[64];
  const int tid = threadIdx.x;

#pragma unroll
  for (int l = 0; l < 2; ++l) {
    const int idx = tid + l * 256;
    const int rr = idx >> 3, cq = idx & 7;
    const __half2* q2 = reinterpret_cast<const __half2*>(
        Qf + (size_t)(r0 + rr) * Dd + h * 64 + cq * 8);
#pragma unroll
    for (int u = 0; u < 4; ++u) {
      const float2 qf = __half22float2(q2[u]);
      Qs[rr][cq * 8 + u * 2] = qf.x; Qs[rr][cq * 8 + u * 2 + 1] = qf.y;
    }
  }
#pragma unroll
  for (int l = 0; l < 4; ++l) {
    const int idx = tid + l * 256;
    const int rr = idx >> 4, cq = idx & 15;
    *reinterpret_cast<float4*>(&KVs[rr][cq * 4]) = *reinterpret_cast<const float4*>(
        &KV[(size_t)bh * 4096 + rr * 64 + cq * 4]);
  }
  if (tid < 64) Ksums[tid] = Ksum[bh * 64 + tid];
  __syncthreads();

  if (tid < 64) {
    float z = 0.f;
#pragma unroll 8
    for (int d = 0; d < 64; ++d) z = fmaf(Qs[tid][d], Ksums[d], z);
    Zs[tid] = 1.f / (z + EPSF);
  }
  __syncthreads();

  const int rx = (tid >> 4) * 4, mx = (tid & 15) * 4;
  float acc[4][4];
#pragma unroll
  for (int i = 0; i < 4; ++i)
#pragma unroll
    for (int j = 0; j < 4; ++j) acc[i][j] = 0.f;

#pragma unroll 4
  for (int d = 0; d < 64; ++d) {
    const float4 vm = *reinterpret_cast<const float4*>(&KVs[d][mx]);
    const float va[4] = {vm.x, vm.y, vm.z, vm.w};
#pragma unroll
    for (int i = 0; i < 4; ++i) {
      const float q = Qs[rx + i][d];
#pragma unroll
      for (int j = 0; j < 4; ++j) acc[i][j] = fmaf(q, va[j], acc[i][j]);
    }
  }

#pragma unroll
  for (int i = 0; i < 4; ++i) {
    const float z = Zs[rx + i];
    short4 hv, lv;
    float o;
    o = acc[i][0] * z; hv.x = f2bf(o); lv.x = f2bf(o - bf2f(hv.x));
    o = acc[i][1] * z; hv.y = f2bf(o); lv.y = f2bf(o - bf2f(hv.y));
    o = acc[i][2] * z; hv.z = f2bf(o); lv.z = f2bf(o - bf2f(hv.z));
    o = acc[i][3] * z; hv.w = f2bf(o); lv.w = f2bf(o - bf2f(hv.w));
    const size_t off = (size_t)(r0 + rx + i) * Dd + h * 64 + mx;
    *reinterpret_cast<short4*>(&Oh[off]) = hv;
    *reinterpret_cast<short4*>(&Ol[off]) = lv;
  }
}

extern "C" void kernel_launch(void* const* d_in, const int* in_sizes, int n_in,
                              void* d_out, int out_size, void* d_ws, size_t ws_size,
                              hipStream_t stream) {
  const float* x  = (const float*)d_in[0];
  const float* Wq = (const float*)d_in[1];
  const float* bq = (const float*)d_in[2];
  const float* Wk = (const float*)d_in[3];
  const float* bk = (const float*)d_in[4];
  const float* Wv = (const float*)d_in[5];
  const float* bv = (const float*)d_in[6];
  const float* Wo = (const float*)d_in[7];
  const float* bo = (const float*)d_in[8];
  float* out = (float*)d_out;

  char* ws = (char*)d_ws;
  const size_t MB = (size_t)1 << 20;
  short*  x_hi  = (short*)(ws);              // 32 MB (later: attn_hi)
  short*  x_lo  = (short*)(ws + 32 * MB);    // 32 MB (later: attn_lo)
  short*  Wt_hi = (short*)(ws + 64 * MB);    // 2 MB (4 x 512x512)
  short*  Wt_lo = (short*)(ws + 66 * MB);    // 2 MB
  __half* Qf    = (__half*)(ws + 68 * MB);   // 32 MB
  __half* Kf    = (__half*)(ws + 100 * MB);  // 32 MB
  __half* Vv    = (__half*)(ws + 132 * MB);  // 32 MB
  float*  KVp   = (float*)(ws + 164 * MB);   // 17 MB
  float*  Ksp   = (float*)(ws + 181 * MB);   // 256 KB
  float*  KV    = (float*)(ws + 182 * MB);   // 1 MB
  float*  Ksum  = (float*)(ws + 183 * MB);   // 16 KB
  short*  attn_hi = x_hi;
  short*  attn_lo = x_lo;
  const size_t WSTEP = (size_t)512 * 512;

  prep_w<<<dim3(16, 16, 4), 256, 0, stream>>>(Wq, Wk, Wv, Wo, Wt_hi, Wt_lo);
  split_x<<<Mtot * Dd / 4 / 256, 256, 0, stream>>>(x, x_hi, x_lo, Mtot * Dd / 4);

  gemm_qkv<<<dim3(Mtot / 256, 6), 512, 0, stream>>>(
      x_hi, x_lo, Wt_hi, Wt_lo, bq, bk, bv, Qf, Kf, Vv);

  kv_stage1<<<dim3(16, 64), 256, 0, stream>>>(Kf, Vv, KVp, Ksp);
  kv_stage2<<<64, 256, 0, stream>>>(KVp, Ksp, KV, Ksum);
  attn_combine<<<dim3(Mtot / 64, Hh), 256, 0, stream>>>(Qf, KV, Ksum, attn_hi, attn_lo);

  gemm_split<<<dim3(Mtot / 256, 2), 512, 0, stream>>>(
      attn_hi, attn_lo, Wt_hi + 3 * WSTEP, Wt_lo + 3 * WSTEP, bo, out);
}